// Round 4
// baseline (216.993 us; speedup 1.0000x reference)
//
#include <hip/hip_runtime.h>

typedef unsigned int u32;

// groups of 4 f32 elements per scale (total elems = cells*85, all %4==0)
#define NG0 5891520u   // 16*76*76*3*85/4
#define NG1 1472880u
#define NG2 368220u
// cells per scale
#define NC0 277248u    // 16*76*76*3
#define NC1 69312u
#define NC2 17328u
#define NBLK 2048u
// pos-kernel blocks per scale (ceil(NC/256))
#define PB0 1083u
#define PB1 271u
#define PB2 68u
#define PBTOT (PB0 + PB1 + PB2)   // 1422

struct NegAcc { float sn; u32 nn; };                      // 8 B
struct PosAcc { float sc, sf, sb; u32 np, mi, pad[3]; };  // 32 B

// ---------------- stage A: streaming neg loss (all elements) ----------------

__device__ __forceinline__ void neg_body(const float4 pv, const float4 gv,
                                         const int4 mv, float& sn, u32& nn)
{
  float d;
  d = gv.x - pv.x; sn = fmaf(d * d, (float)mv.x, sn); nn += (u32)mv.x;
  d = gv.y - pv.y; sn = fmaf(d * d, (float)mv.y, sn); nn += (u32)mv.y;
  d = gv.z - pv.z; sn = fmaf(d * d, (float)mv.z, sn); nn += (u32)mv.z;
  d = gv.w - pv.w; sn = fmaf(d * d, (float)mv.w, sn); nn += (u32)mv.w;
}

__device__ __forceinline__ void neg_scale(
    const float* __restrict__ pred, const float* __restrict__ gt,
    const int* __restrict__ mneg, u32 n, u32 tid, u32 stride,
    NegAcc* __restrict__ slot)
{
  const float4* __restrict__ p4 = (const float4*)pred;
  const float4* __restrict__ g4 = (const float4*)gt;
  const int4*   __restrict__ m4 = (const int4*)mneg;
  float sn = 0.f; u32 nn = 0;
  const u32 iters = n / stride;   // uniform, counted loop -> loads batch
  u32 i = 0;
  for (; i + 2 <= iters; i += 2) {
    u32 ga = tid + i * stride;
    u32 gb = ga + stride;
    float4 pa = p4[ga]; float4 qa = g4[ga]; int4 ma = m4[ga];
    float4 pb = p4[gb]; float4 qb = g4[gb]; int4 mb = m4[gb];
    neg_body(pa, qa, ma, sn, nn);
    neg_body(pb, qb, mb, sn, nn);
  }
  if (i < iters) {
    u32 ga = tid + i * stride;
    neg_body(p4[ga], g4[ga], m4[ga], sn, nn);
  }
  u32 gl = tid + iters * stride;
  if (gl < n) {
    neg_body(p4[gl], g4[gl], m4[gl], sn, nn);
  }
  #pragma unroll
  for (int o = 32; o > 0; o >>= 1) {
    sn += __shfl_down(sn, o);
    nn += __shfl_down((int)nn, o);
  }
  __shared__ float shf[4];
  __shared__ u32 shu[4];
  const int wave = threadIdx.x >> 6, lane = threadIdx.x & 63;
  if (lane == 0) { shf[wave] = sn; shu[wave] = nn; }
  __syncthreads();
  if (threadIdx.x == 0) {
    NegAcc a;
    a.sn = shf[0] + shf[1] + shf[2] + shf[3];
    a.nn = shu[0] + shu[1] + shu[2] + shu[3];
    *slot = a;
  }
  __syncthreads();   // shared reused by next scale
}

__global__ __launch_bounds__(256) void yolo_neg(
    const float* __restrict__ pred0, const float* __restrict__ gt0, const int* __restrict__ mn0,
    const float* __restrict__ pred1, const float* __restrict__ gt1, const int* __restrict__ mn1,
    const float* __restrict__ pred2, const float* __restrict__ gt2, const int* __restrict__ mn2,
    NegAcc* __restrict__ neg)
{
  const u32 tid = blockIdx.x * blockDim.x + threadIdx.x;
  const u32 stride = gridDim.x * blockDim.x;
  neg_scale(pred0, gt0, mn0, NG0, tid, stride, &neg[0 * NBLK + blockIdx.x]);
  neg_scale(pred1, gt1, mn1, NG1, tid, stride, &neg[1 * NBLK + blockIdx.x]);
  neg_scale(pred2, gt2, mn2, NG2, tid, stride, &neg[2 * NBLK + blockIdx.x]);
}

// ---------------- stage B: positive cells (1% density) ----------------

__global__ __launch_bounds__(256) void yolo_pos(
    const float* __restrict__ pred0, const float* __restrict__ gt0, const int* __restrict__ mp0,
    const float* __restrict__ pred1, const float* __restrict__ gt1, const int* __restrict__ mp1,
    const float* __restrict__ pred2, const float* __restrict__ gt2, const int* __restrict__ mp2,
    PosAcc* __restrict__ pos)
{
  const u32 b = blockIdx.x;
  const float* pred; const float* gtp; const int* mp; u32 nc, cell0;
  if (b < PB0)            { pred = pred0; gtp = gt0; mp = mp0; nc = NC0; cell0 = b * 256u; }
  else if (b < PB0 + PB1) { pred = pred1; gtp = gt1; mp = mp1; nc = NC1; cell0 = (b - PB0) * 256u; }
  else                    { pred = pred2; gtp = gt2; mp = mp2; nc = NC2; cell0 = (b - PB0 - PB1) * 256u; }

  const u32 cell = cell0 + threadIdx.x;
  float sc = 0.f, sf = 0.f, sb = 0.f; u32 np = 0, mi = 0;
  if (cell < nc && mp[cell] != 0) {
    np = 1; mi = cell;
    const float* __restrict__ pp = pred + (size_t)cell * 85u;
    const float* __restrict__ gg = gtp  + (size_t)cell * 85u;
    #pragma unroll
    for (int ch = 0; ch < 4; ++ch) {
      float x = pp[ch], z = gg[ch], d = z - x;
      sc += d * d;
    }
    { float x = pp[4], z = gg[4], d = z - x; sf = d * d; }
    #pragma unroll 16
    for (int ch = 5; ch < 85; ++ch) {
      float x = pp[ch], z = gg[ch];
      sb += fmaxf(x, 0.f) - x * z + log1pf(__expf(-fabsf(x)));
    }
  }
  #pragma unroll
  for (int o = 32; o > 0; o >>= 1) {
    sc += __shfl_down(sc, o);
    sf += __shfl_down(sf, o);
    sb += __shfl_down(sb, o);
    np += __shfl_down((int)np, o);
    u32 om = __shfl_down((int)mi, o);
    mi = om > mi ? om : mi;
  }
  __shared__ float shf[3][4];
  __shared__ u32 shu[2][4];
  const int wave = threadIdx.x >> 6, lane = threadIdx.x & 63;
  if (lane == 0) {
    shf[0][wave] = sc; shf[1][wave] = sf; shf[2][wave] = sb;
    shu[0][wave] = np; shu[1][wave] = mi;
  }
  __syncthreads();
  if (threadIdx.x == 0) {
    PosAcc a = {0.f, 0.f, 0.f, 0u, 0u, {0u, 0u, 0u}};
    #pragma unroll
    for (int w = 0; w < 4; ++w) {
      a.sc += shf[0][w]; a.sf += shf[1][w]; a.sb += shf[2][w];
      a.np += shu[0][w];
      a.mi = shu[1][w] > a.mi ? shu[1][w] : a.mi;
    }
    pos[b] = a;
  }
}

// ---------------- stage C: final reduce + loss ----------------

__global__ __launch_bounds__(256) void yolo_final(
    const NegAcc* __restrict__ neg, const PosAcc* __restrict__ pos,
    const float* __restrict__ mod0, const float* __restrict__ mod1,
    const float* __restrict__ mod2, float* __restrict__ out)
{
  const float* mods[3] = {mod0, mod1, mod2};
  const u32 pbase[3] = {0u, PB0, PB0 + PB1};
  const u32 pcnt[3]  = {PB0, PB1, PB2};
  __shared__ float shf[4][4];
  __shared__ u32 shu[3][4];
  const int wave = threadIdx.x >> 6, lane = threadIdx.x & 63;
  float loss = 0.f;   // only thread 0's copy matters
  for (int s = 0; s < 3; ++s) {
    float sn = 0.f, sc = 0.f, sf = 0.f, sb = 0.f;
    u32 nn = 0, np = 0, mi = 0;
    for (u32 t = threadIdx.x; t < NBLK; t += 256u) {
      NegAcc a = neg[(u32)s * NBLK + t];
      sn += a.sn; nn += a.nn;
    }
    for (u32 t = threadIdx.x; t < pcnt[s]; t += 256u) {
      PosAcc a = pos[pbase[s] + t];
      sc += a.sc; sf += a.sf; sb += a.sb; np += a.np;
      mi = a.mi > mi ? a.mi : mi;
    }
    #pragma unroll
    for (int o = 32; o > 0; o >>= 1) {
      sn += __shfl_down(sn, o);
      sc += __shfl_down(sc, o);
      sf += __shfl_down(sf, o);
      sb += __shfl_down(sb, o);
      nn += __shfl_down((int)nn, o);
      np += __shfl_down((int)np, o);
      u32 om = __shfl_down((int)mi, o);
      mi = om > mi ? om : mi;
    }
    if (lane == 0) {
      shf[0][wave] = sn; shf[1][wave] = sc; shf[2][wave] = sf; shf[3][wave] = sb;
      shu[0][wave] = nn; shu[1][wave] = np; shu[2][wave] = mi;
    }
    __syncthreads();
    if (threadIdx.x == 0) {
      float Sn = 0.f, Sc = 0.f, Sf = 0.f, Sb = 0.f;
      u32 Nn = 0, Np = 0, Mi = 0;
      #pragma unroll
      for (int w = 0; w < 4; ++w) {
        Sn += shf[0][w]; Sc += shf[1][w]; Sf += shf[2][w]; Sb += shf[3][w];
        Nn += shu[0][w]; Np += shu[1][w];
        Mi = shu[2][w] > Mi ? shu[2][w] : Mi;
      }
      if (Np > 0u) {
        float w_last = mods[s][(size_t)Mi * 6u];  // modulus.reshape(-1,6)[idx_last,0]
        loss += (w_last * Sc + Sf + Sb * (1.f / 80.f)) / (float)Np;
      }
      if (Nn > 0u) loss += 3.0f * Sn / (float)Nn;
    }
    __syncthreads();
  }
  if (threadIdx.x == 0) out[0] = loss;
}

extern "C" void kernel_launch(void* const* d_in, const int* in_sizes, int n_in,
                              void* d_out, int out_size, void* d_ws, size_t ws_size,
                              hipStream_t stream)
{
  const float* pred0 = (const float*)d_in[0];
  const float* gt0   = (const float*)d_in[1];
  const float* mod0  = (const float*)d_in[2];
  const int*   mp0   = (const int*)d_in[3];
  const int*   mn0   = (const int*)d_in[4];
  const float* pred1 = (const float*)d_in[5];
  const float* gt1   = (const float*)d_in[6];
  const float* mod1  = (const float*)d_in[7];
  const int*   mp1   = (const int*)d_in[8];
  const int*   mn1   = (const int*)d_in[9];
  const float* pred2 = (const float*)d_in[10];
  const float* gt2   = (const float*)d_in[11];
  const float* mod2  = (const float*)d_in[12];
  const int*   mp2   = (const int*)d_in[13];
  const int*   mn2   = (const int*)d_in[14];

  NegAcc* neg = (NegAcc*)d_ws;                           // 3*2048*8  = 48 KB
  PosAcc* pos = (PosAcc*)((char*)d_ws + 3 * NBLK * sizeof(NegAcc));  // 1422*32 B

  yolo_neg<<<NBLK, 256, 0, stream>>>(pred0, gt0, mn0,
                                     pred1, gt1, mn1,
                                     pred2, gt2, mn2, neg);
  yolo_pos<<<PBTOT, 256, 0, stream>>>(pred0, gt0, mp0,
                                      pred1, gt1, mp1,
                                      pred2, gt2, mp2, pos);
  yolo_final<<<1, 256, 0, stream>>>(neg, pos, mod0, mod1, mod2, (float*)d_out);
}

// Round 5
// 88.635 us; speedup vs baseline: 2.4482x; 2.4482x over previous
//
#include <hip/hip_runtime.h>

typedef unsigned int u32;
typedef unsigned long long u64;

// groups of 4 f32 elements per scale (total elems = cells*85, all %4==0)
#define NG0 5891520u   // 16*76*76*3*85/4
#define NG1 1472880u
#define NG2 368220u
// cells per scale
#define NC0 277248u    // 16*76*76*3
#define NC1 69312u
#define NC2 17328u
#define NBLK 2048u
// pos-kernel blocks per scale (ceil(NC/256))
#define PB0 1083u
#define PB1 271u
#define PB2 68u
#define PBTOT (PB0 + PB1 + PB2)   // 1422

struct NegAcc { float sn; u32 nn; };                      // 8 B
struct PosAcc { float sc, sf, sb; u32 np, mi, pad[3]; };  // 32 B

// ---------------- stage A: streaming neg loss (all elements) ----------------

__device__ __forceinline__ void neg_body(const float4 pv, const float4 gv,
                                         const int4 mv, float& sn, u32& nn)
{
  float d;
  d = gv.x - pv.x; sn = fmaf(d * d, (float)mv.x, sn); nn += (u32)mv.x;
  d = gv.y - pv.y; sn = fmaf(d * d, (float)mv.y, sn); nn += (u32)mv.y;
  d = gv.z - pv.z; sn = fmaf(d * d, (float)mv.z, sn); nn += (u32)mv.z;
  d = gv.w - pv.w; sn = fmaf(d * d, (float)mv.w, sn); nn += (u32)mv.w;
}

__device__ __forceinline__ void neg_scale(
    const float* __restrict__ pred, const float* __restrict__ gt,
    const int* __restrict__ mneg, u32 n, u32 tid, u32 stride,
    NegAcc* __restrict__ slot)
{
  const float4* __restrict__ p4 = (const float4*)pred;
  const float4* __restrict__ g4 = (const float4*)gt;
  const int4*   __restrict__ m4 = (const int4*)mneg;
  float sn = 0.f; u32 nn = 0;
  const u32 iters = n / stride;   // uniform counted loop
  u32 i = 0;
  // x4 unroll: 12 independent 16B loads in flight before any use
  for (; i + 4 <= iters; i += 4) {
    u32 g0 = tid + i * stride, g1 = g0 + stride, g2 = g1 + stride, g3 = g2 + stride;
    float4 pa = p4[g0], pb = p4[g1], pc = p4[g2], pd = p4[g3];
    float4 qa = g4[g0], qb = g4[g1], qc = g4[g2], qd = g4[g3];
    int4   ma = m4[g0], mb = m4[g1], mc = m4[g2], md = m4[g3];
    neg_body(pa, qa, ma, sn, nn);
    neg_body(pb, qb, mb, sn, nn);
    neg_body(pc, qc, mc, sn, nn);
    neg_body(pd, qd, md, sn, nn);
  }
  for (; i < iters; ++i) {
    u32 ga = tid + i * stride;
    neg_body(p4[ga], g4[ga], m4[ga], sn, nn);
  }
  u32 gl = tid + iters * stride;
  if (gl < n) {
    neg_body(p4[gl], g4[gl], m4[gl], sn, nn);
  }
  #pragma unroll
  for (int o = 32; o > 0; o >>= 1) {
    sn += __shfl_down(sn, o);
    nn += __shfl_down((int)nn, o);
  }
  __shared__ float shf[4];
  __shared__ u32 shu[4];
  const int wave = threadIdx.x >> 6, lane = threadIdx.x & 63;
  if (lane == 0) { shf[wave] = sn; shu[wave] = nn; }
  __syncthreads();
  if (threadIdx.x == 0) {
    NegAcc a;
    a.sn = shf[0] + shf[1] + shf[2] + shf[3];
    a.nn = shu[0] + shu[1] + shu[2] + shu[3];
    *slot = a;
  }
  __syncthreads();   // shared reused by next scale
}

__global__ __launch_bounds__(256) void yolo_neg(
    const float* __restrict__ pred0, const float* __restrict__ gt0, const int* __restrict__ mn0,
    const float* __restrict__ pred1, const float* __restrict__ gt1, const int* __restrict__ mn1,
    const float* __restrict__ pred2, const float* __restrict__ gt2, const int* __restrict__ mn2,
    NegAcc* __restrict__ neg)
{
  const u32 tid = blockIdx.x * blockDim.x + threadIdx.x;
  const u32 stride = gridDim.x * blockDim.x;
  neg_scale(pred0, gt0, mn0, NG0, tid, stride, &neg[0 * NBLK + blockIdx.x]);
  neg_scale(pred1, gt1, mn1, NG1, tid, stride, &neg[1 * NBLK + blockIdx.x]);
  neg_scale(pred2, gt2, mn2, NG2, tid, stride, &neg[2 * NBLK + blockIdx.x]);
}

// ---------- stage B: positive cells (1% density, ballot-cooperative) --------
// Each wave ballots its 64 cells; for each active cell, ALL 64 lanes process
// the 85 channels in parallel (lane l -> ch l, and ch 64+l for l<21).
// Per-lane accumulators, single wave-reduce in the epilogue.

__global__ __launch_bounds__(256) void yolo_pos(
    const float* __restrict__ pred0, const float* __restrict__ gt0, const int* __restrict__ mp0,
    const float* __restrict__ pred1, const float* __restrict__ gt1, const int* __restrict__ mp1,
    const float* __restrict__ pred2, const float* __restrict__ gt2, const int* __restrict__ mp2,
    PosAcc* __restrict__ pos)
{
  const u32 b = blockIdx.x;
  const float* pred; const float* gtp; const int* mp; u32 nc, cell0;
  if (b < PB0)            { pred = pred0; gtp = gt0; mp = mp0; nc = NC0; cell0 = b * 256u; }
  else if (b < PB0 + PB1) { pred = pred1; gtp = gt1; mp = mp1; nc = NC1; cell0 = (b - PB0) * 256u; }
  else                    { pred = pred2; gtp = gt2; mp = mp2; nc = NC2; cell0 = (b - PB0 - PB1) * 256u; }

  const int lane = threadIdx.x & 63;
  const int wave = threadIdx.x >> 6;
  const u32 cell = cell0 + threadIdx.x;
  const u32 wavecell0 = cell0 + (u32)(threadIdx.x & ~63u);

  const bool active = (cell < nc) && (mp[cell] != 0);
  u64 bal = __ballot(active);

  float sc = 0.f, sf = 0.f, sb = 0.f;
  u32 np = active ? 1u : 0u;
  u32 mi = active ? cell : 0u;

  while (bal) {
    const int src = __ffsll(bal) - 1;
    bal &= bal - 1ull;
    const u32 c = wavecell0 + (u32)src;
    const float* __restrict__ pp = pred + (size_t)c * 85u;
    const float* __restrict__ gg = gtp  + (size_t)c * 85u;
    float x0 = pp[lane], z0 = gg[lane];
    float d0 = z0 - x0;
    // bce with native transcendentals (|err| ~1e-6 per term, fine vs 0.68 abs)
    float b0 = fmaxf(x0, 0.f) - x0 * z0 + __logf(1.f + __expf(-fabsf(x0)));
    if (lane < 4)       sc += d0 * d0;
    else if (lane == 4) sf += d0 * d0;
    else                sb += b0;
    if (lane < 21) {
      float x1 = pp[64 + lane], z1 = gg[64 + lane];
      sb += fmaxf(x1, 0.f) - x1 * z1 + __logf(1.f + __expf(-fabsf(x1)));
    }
  }

  #pragma unroll
  for (int o = 32; o > 0; o >>= 1) {
    sc += __shfl_down(sc, o);
    sf += __shfl_down(sf, o);
    sb += __shfl_down(sb, o);
    np += __shfl_down((int)np, o);
    u32 om = __shfl_down((int)mi, o);
    mi = om > mi ? om : mi;
  }
  __shared__ float shf[3][4];
  __shared__ u32 shu[2][4];
  if (lane == 0) {
    shf[0][wave] = sc; shf[1][wave] = sf; shf[2][wave] = sb;
    shu[0][wave] = np; shu[1][wave] = mi;
  }
  __syncthreads();
  if (threadIdx.x == 0) {
    PosAcc a = {0.f, 0.f, 0.f, 0u, 0u, {0u, 0u, 0u}};
    #pragma unroll
    for (int w = 0; w < 4; ++w) {
      a.sc += shf[0][w]; a.sf += shf[1][w]; a.sb += shf[2][w];
      a.np += shu[0][w];
      a.mi = shu[1][w] > a.mi ? shu[1][w] : a.mi;
    }
    pos[b] = a;
  }
}

// ---------------- stage C: final reduce + loss ----------------

__global__ __launch_bounds__(256) void yolo_final(
    const NegAcc* __restrict__ neg, const PosAcc* __restrict__ pos,
    const float* __restrict__ mod0, const float* __restrict__ mod1,
    const float* __restrict__ mod2, float* __restrict__ out)
{
  const float* mods[3] = {mod0, mod1, mod2};
  const u32 pbase[3] = {0u, PB0, PB0 + PB1};
  const u32 pcnt[3]  = {PB0, PB1, PB2};
  __shared__ float shf[4][4];
  __shared__ u32 shu[3][4];
  const int wave = threadIdx.x >> 6, lane = threadIdx.x & 63;
  float loss = 0.f;   // only thread 0's copy matters
  for (int s = 0; s < 3; ++s) {
    float sn = 0.f, sc = 0.f, sf = 0.f, sb = 0.f;
    u32 nn = 0, np = 0, mi = 0;
    for (u32 t = threadIdx.x; t < NBLK; t += 256u) {
      NegAcc a = neg[(u32)s * NBLK + t];
      sn += a.sn; nn += a.nn;
    }
    for (u32 t = threadIdx.x; t < pcnt[s]; t += 256u) {
      PosAcc a = pos[pbase[s] + t];
      sc += a.sc; sf += a.sf; sb += a.sb; np += a.np;
      mi = a.mi > mi ? a.mi : mi;
    }
    #pragma unroll
    for (int o = 32; o > 0; o >>= 1) {
      sn += __shfl_down(sn, o);
      sc += __shfl_down(sc, o);
      sf += __shfl_down(sf, o);
      sb += __shfl_down(sb, o);
      nn += __shfl_down((int)nn, o);
      np += __shfl_down((int)np, o);
      u32 om = __shfl_down((int)mi, o);
      mi = om > mi ? om : mi;
    }
    if (lane == 0) {
      shf[0][wave] = sn; shf[1][wave] = sc; shf[2][wave] = sf; shf[3][wave] = sb;
      shu[0][wave] = nn; shu[1][wave] = np; shu[2][wave] = mi;
    }
    __syncthreads();
    if (threadIdx.x == 0) {
      float Sn = 0.f, Sc = 0.f, Sf = 0.f, Sb = 0.f;
      u32 Nn = 0, Np = 0, Mi = 0;
      #pragma unroll
      for (int w = 0; w < 4; ++w) {
        Sn += shf[0][w]; Sc += shf[1][w]; Sf += shf[2][w]; Sb += shf[3][w];
        Nn += shu[0][w]; Np += shu[1][w];
        Mi = shu[2][w] > Mi ? shu[2][w] : Mi;
      }
      if (Np > 0u) {
        float w_last = mods[s][(size_t)Mi * 6u];  // modulus.reshape(-1,6)[idx_last,0]
        loss += (w_last * Sc + Sf + Sb * (1.f / 80.f)) / (float)Np;
      }
      if (Nn > 0u) loss += 3.0f * Sn / (float)Nn;
    }
    __syncthreads();
  }
  if (threadIdx.x == 0) out[0] = loss;
}

extern "C" void kernel_launch(void* const* d_in, const int* in_sizes, int n_in,
                              void* d_out, int out_size, void* d_ws, size_t ws_size,
                              hipStream_t stream)
{
  const float* pred0 = (const float*)d_in[0];
  const float* gt0   = (const float*)d_in[1];
  const float* mod0  = (const float*)d_in[2];
  const int*   mp0   = (const int*)d_in[3];
  const int*   mn0   = (const int*)d_in[4];
  const float* pred1 = (const float*)d_in[5];
  const float* gt1   = (const float*)d_in[6];
  const float* mod1  = (const float*)d_in[7];
  const int*   mp1   = (const int*)d_in[8];
  const int*   mn1   = (const int*)d_in[9];
  const float* pred2 = (const float*)d_in[10];
  const float* gt2   = (const float*)d_in[11];
  const float* mod2  = (const float*)d_in[12];
  const int*   mp2   = (const int*)d_in[13];
  const int*   mn2   = (const int*)d_in[14];

  NegAcc* neg = (NegAcc*)d_ws;                                       // 48 KB
  PosAcc* pos = (PosAcc*)((char*)d_ws + 3 * NBLK * sizeof(NegAcc));  // 45.5 KB

  yolo_neg<<<NBLK, 256, 0, stream>>>(pred0, gt0, mn0,
                                     pred1, gt1, mn1,
                                     pred2, gt2, mn2, neg);
  yolo_pos<<<PBTOT, 256, 0, stream>>>(pred0, gt0, mp0,
                                      pred1, gt1, mp1,
                                      pred2, gt2, mp2, pos);
  yolo_final<<<1, 256, 0, stream>>>(neg, pos, mod0, mod1, mod2, (float*)d_out);
}

// Round 6
// 86.429 us; speedup vs baseline: 2.5106x; 1.0255x over previous
//
#include <hip/hip_runtime.h>

typedef unsigned int u32;
typedef unsigned long long u64;

// groups of 4 f32 elements per scale (total elems = cells*85, all %4==0)
#define NG0 5891520u   // 16*76*76*3*85/4
#define NG1 1472880u
#define NG2 368220u
// cells per scale
#define NC0 277248u    // 16*76*76*3
#define NC1 69312u
#define NC2 17328u
#define NBLK 2048u
// pos blocks per scale (ceil(NC/256)) — blocks [0,PBTOT) also do pos work
#define PB0 1083u
#define PB1 271u
#define PB2 68u
#define PBTOT (PB0 + PB1 + PB2)   // 1422

struct BlockAcc {
  float sn0, sn1, sn2;     // neg sum per scale
  u32   nn0, nn1, nn2;     // neg count per scale
  float sc, sf, sb;        // pos sums (this block's single scale)
  u32   np, mi;            // pos count, max cell idx
  u32   pad[5];            // -> 64 B
};

__device__ __forceinline__ void neg_body(const float4 pv, const float4 gv,
                                         const int4 mv, float& sn, u32& nn)
{
  float d;
  d = gv.x - pv.x; sn = fmaf(d * d, (float)mv.x, sn); nn += (u32)mv.x;
  d = gv.y - pv.y; sn = fmaf(d * d, (float)mv.y, sn); nn += (u32)mv.y;
  d = gv.z - pv.z; sn = fmaf(d * d, (float)mv.z, sn); nn += (u32)mv.z;
  d = gv.w - pv.w; sn = fmaf(d * d, (float)mv.w, sn); nn += (u32)mv.w;
}

// streaming pass over one scale, accumulate into regs (no commit, no barrier)
__device__ __forceinline__ void neg_stream(
    const float* __restrict__ pred, const float* __restrict__ gt,
    const int* __restrict__ mneg, u32 n, u32 tid, u32 stride,
    float& sn, u32& nn)
{
  const float4* __restrict__ p4 = (const float4*)pred;
  const float4* __restrict__ g4 = (const float4*)gt;
  const int4*   __restrict__ m4 = (const int4*)mneg;
  const u32 iters = n / stride;   // uniform counted loop
  u32 i = 0;
  // x2 unroll (x4 regressed in R5: 4 streams 8MB apart per wave hurt locality)
  for (; i + 2 <= iters; i += 2) {
    u32 ga = tid + i * stride, gb = ga + stride;
    float4 pa = p4[ga], qa = g4[ga]; int4 ma = m4[ga];
    float4 pb = p4[gb], qb = g4[gb]; int4 mb = m4[gb];
    neg_body(pa, qa, ma, sn, nn);
    neg_body(pb, qb, mb, sn, nn);
  }
  if (i < iters) {
    u32 ga = tid + i * stride;
    neg_body(p4[ga], g4[ga], m4[ga], sn, nn);
  }
  u32 gl = tid + iters * stride;
  if (gl < n) neg_body(p4[gl], g4[gl], m4[gl], sn, nn);
}

__global__ __launch_bounds__(256) void yolo_fused(
    const float* __restrict__ pred0, const float* __restrict__ gt0,
    const int* __restrict__ mp0, const int* __restrict__ mn0,
    const float* __restrict__ pred1, const float* __restrict__ gt1,
    const int* __restrict__ mp1, const int* __restrict__ mn1,
    const float* __restrict__ pred2, const float* __restrict__ gt2,
    const int* __restrict__ mp2, const int* __restrict__ mn2,
    BlockAcc* __restrict__ ws)
{
  const u32 tid = blockIdx.x * blockDim.x + threadIdx.x;
  const u32 stride = gridDim.x * blockDim.x;

  // ---- phase 1: streaming neg over all three scales, register-resident ----
  float sn0 = 0.f, sn1 = 0.f, sn2 = 0.f;
  u32 nn0 = 0, nn1 = 0, nn2 = 0;
  neg_stream(pred0, gt0, mn0, NG0, tid, stride, sn0, nn0);
  neg_stream(pred1, gt1, mn1, NG1, tid, stride, sn1, nn1);
  neg_stream(pred2, gt2, mn2, NG2, tid, stride, sn2, nn2);

  // ---- phase 2: ballot-cooperative pos cells (blocks < PBTOT only) ----
  float sc = 0.f, sf = 0.f, sb = 0.f;
  u32 np = 0, mi = 0;
  const u32 b = blockIdx.x;
  if (b < PBTOT) {
    const float* pred; const float* gtp; const int* mp; u32 nc, cell0;
    if (b < PB0)            { pred = pred0; gtp = gt0; mp = mp0; nc = NC0; cell0 = b * 256u; }
    else if (b < PB0 + PB1) { pred = pred1; gtp = gt1; mp = mp1; nc = NC1; cell0 = (b - PB0) * 256u; }
    else                    { pred = pred2; gtp = gt2; mp = mp2; nc = NC2; cell0 = (b - PB0 - PB1) * 256u; }

    const int lane = threadIdx.x & 63;
    const u32 cell = cell0 + threadIdx.x;
    const u32 wavecell0 = cell0 + (u32)(threadIdx.x & ~63u);
    const bool active = (cell < nc) && (mp[cell] != 0);
    u64 bal = __ballot(active);
    np = active ? 1u : 0u;
    mi = active ? cell : 0u;

    while (bal) {
      const int src = __ffsll(bal) - 1;
      bal &= bal - 1ull;
      const u32 c = wavecell0 + (u32)src;
      const float* __restrict__ pp = pred + (size_t)c * 85u;
      const float* __restrict__ gg = gtp  + (size_t)c * 85u;
      float x0 = pp[lane], z0 = gg[lane];
      float d0 = z0 - x0;
      float b0 = fmaxf(x0, 0.f) - x0 * z0 + __logf(1.f + __expf(-fabsf(x0)));
      if (lane < 4)       sc += d0 * d0;
      else if (lane == 4) sf += d0 * d0;
      else                sb += b0;
      if (lane < 21) {
        float x1 = pp[64 + lane], z1 = gg[64 + lane];
        sb += fmaxf(x1, 0.f) - x1 * z1 + __logf(1.f + __expf(-fabsf(x1)));
      }
    }
  }

  // ---- phase 3: single block-reduce + one 64B commit ----
  #pragma unroll
  for (int o = 32; o > 0; o >>= 1) {
    sn0 += __shfl_down(sn0, o);
    sn1 += __shfl_down(sn1, o);
    sn2 += __shfl_down(sn2, o);
    nn0 += __shfl_down((int)nn0, o);
    nn1 += __shfl_down((int)nn1, o);
    nn2 += __shfl_down((int)nn2, o);
    sc  += __shfl_down(sc, o);
    sf  += __shfl_down(sf, o);
    sb  += __shfl_down(sb, o);
    np  += __shfl_down((int)np, o);
    u32 om = __shfl_down((int)mi, o);
    mi = om > mi ? om : mi;
  }
  __shared__ float shf[6][4];
  __shared__ u32 shu[5][4];
  const int wave = threadIdx.x >> 6, lane = threadIdx.x & 63;
  if (lane == 0) {
    shf[0][wave] = sn0; shf[1][wave] = sn1; shf[2][wave] = sn2;
    shf[3][wave] = sc;  shf[4][wave] = sf;  shf[5][wave] = sb;
    shu[0][wave] = nn0; shu[1][wave] = nn1; shu[2][wave] = nn2;
    shu[3][wave] = np;  shu[4][wave] = mi;
  }
  __syncthreads();
  if (threadIdx.x == 0) {
    BlockAcc a = {};
    #pragma unroll
    for (int w = 0; w < 4; ++w) {
      a.sn0 += shf[0][w]; a.sn1 += shf[1][w]; a.sn2 += shf[2][w];
      a.sc  += shf[3][w]; a.sf  += shf[4][w]; a.sb  += shf[5][w];
      a.nn0 += shu[0][w]; a.nn1 += shu[1][w]; a.nn2 += shu[2][w];
      a.np  += shu[3][w];
      a.mi = shu[4][w] > a.mi ? shu[4][w] : a.mi;
    }
    ws[blockIdx.x] = a;
  }
}

// single-wave final: reduce 2048 BlockAccs, per-scale pos via block ranges
__global__ __launch_bounds__(64) void yolo_final(
    const BlockAcc* __restrict__ ws,
    const float* __restrict__ mod0, const float* __restrict__ mod1,
    const float* __restrict__ mod2, float* __restrict__ out)
{
  const int lane = threadIdx.x;
  float sn0 = 0.f, sn1 = 0.f, sn2 = 0.f;
  float nn0 = 0.f, nn1 = 0.f, nn2 = 0.f;  // counts fit exactly in f32 (<16M)
  u32 in0 = 0, in1 = 0, in2 = 0;
  for (u32 t = lane; t < NBLK; t += 64u) {
    const BlockAcc a = ws[t];
    sn0 += a.sn0; sn1 += a.sn1; sn2 += a.sn2;
    in0 += a.nn0; in1 += a.nn1; in2 += a.nn2;
  }
  nn0 = (float)in0; nn1 = (float)in1; nn2 = (float)in2;

  float sc0 = 0.f, sf0 = 0.f, sb0 = 0.f; u32 np0 = 0, mi0 = 0;
  for (u32 t = lane; t < PB0; t += 64u) {
    const BlockAcc a = ws[t];
    sc0 += a.sc; sf0 += a.sf; sb0 += a.sb; np0 += a.np;
    mi0 = a.mi > mi0 ? a.mi : mi0;
  }
  float sc1 = 0.f, sf1 = 0.f, sb1 = 0.f; u32 np1 = 0, mi1 = 0;
  for (u32 t = PB0 + lane; t < PB0 + PB1; t += 64u) {
    const BlockAcc a = ws[t];
    sc1 += a.sc; sf1 += a.sf; sb1 += a.sb; np1 += a.np;
    mi1 = a.mi > mi1 ? a.mi : mi1;
  }
  float sc2 = 0.f, sf2 = 0.f, sb2 = 0.f; u32 np2 = 0, mi2 = 0;
  for (u32 t = PB0 + PB1 + lane; t < PBTOT; t += 64u) {
    const BlockAcc a = ws[t];
    sc2 += a.sc; sf2 += a.sf; sb2 += a.sb; np2 += a.np;
    mi2 = a.mi > mi2 ? a.mi : mi2;
  }

  #pragma unroll
  for (int o = 32; o > 0; o >>= 1) {
    sn0 += __shfl_down(sn0, o); sn1 += __shfl_down(sn1, o); sn2 += __shfl_down(sn2, o);
    nn0 += __shfl_down(nn0, o); nn1 += __shfl_down(nn1, o); nn2 += __shfl_down(nn2, o);
    sc0 += __shfl_down(sc0, o); sf0 += __shfl_down(sf0, o); sb0 += __shfl_down(sb0, o);
    sc1 += __shfl_down(sc1, o); sf1 += __shfl_down(sf1, o); sb1 += __shfl_down(sb1, o);
    sc2 += __shfl_down(sc2, o); sf2 += __shfl_down(sf2, o); sb2 += __shfl_down(sb2, o);
    np0 += __shfl_down((int)np0, o); np1 += __shfl_down((int)np1, o); np2 += __shfl_down((int)np2, o);
    u32 m0 = __shfl_down((int)mi0, o); mi0 = m0 > mi0 ? m0 : mi0;
    u32 m1 = __shfl_down((int)mi1, o); mi1 = m1 > mi1 ? m1 : mi1;
    u32 m2 = __shfl_down((int)mi2, o); mi2 = m2 > mi2 ? m2 : mi2;
  }

  if (lane == 0) {
    float loss = 0.f;
    if (np0 > 0u)
      loss += (mod0[(size_t)mi0 * 6u] * sc0 + sf0 + sb0 * (1.f / 80.f)) / (float)np0;
    if (nn0 > 0.f) loss += 3.0f * sn0 / nn0;
    if (np1 > 0u)
      loss += (mod1[(size_t)mi1 * 6u] * sc1 + sf1 + sb1 * (1.f / 80.f)) / (float)np1;
    if (nn1 > 0.f) loss += 3.0f * sn1 / nn1;
    if (np2 > 0u)
      loss += (mod2[(size_t)mi2 * 6u] * sc2 + sf2 + sb2 * (1.f / 80.f)) / (float)np2;
    if (nn2 > 0.f) loss += 3.0f * sn2 / nn2;
    out[0] = loss;
  }
}

extern "C" void kernel_launch(void* const* d_in, const int* in_sizes, int n_in,
                              void* d_out, int out_size, void* d_ws, size_t ws_size,
                              hipStream_t stream)
{
  const float* pred0 = (const float*)d_in[0];
  const float* gt0   = (const float*)d_in[1];
  const float* mod0  = (const float*)d_in[2];
  const int*   mp0   = (const int*)d_in[3];
  const int*   mn0   = (const int*)d_in[4];
  const float* pred1 = (const float*)d_in[5];
  const float* gt1   = (const float*)d_in[6];
  const float* mod1  = (const float*)d_in[7];
  const int*   mp1   = (const int*)d_in[8];
  const int*   mn1   = (const int*)d_in[9];
  const float* pred2 = (const float*)d_in[10];
  const float* gt2   = (const float*)d_in[11];
  const float* mod2  = (const float*)d_in[12];
  const int*   mp2   = (const int*)d_in[13];
  const int*   mn2   = (const int*)d_in[14];

  BlockAcc* ws = (BlockAcc*)d_ws;   // 2048 * 64 B = 128 KB, every slot written

  yolo_fused<<<NBLK, 256, 0, stream>>>(pred0, gt0, mp0, mn0,
                                       pred1, gt1, mp1, mn1,
                                       pred2, gt2, mp2, mn2, ws);
  yolo_final<<<1, 64, 0, stream>>>(ws, mod0, mod1, mod2, (float*)d_out);
}